// Round 1
// baseline (1283.376 us; speedup 1.0000x reference)
//
#include <hip/hip_runtime.h>

#define SQ 4096      // sequence length = 64*64
#define CCH 256      // channels
#define NH 8         // heads
#define HD 32        // head dim
#define LN_EPS 1e-5f

// ---------------------------------------------------------------------------
// Tiled GEMM, TN variant: C[M,N] = A^T @ B + bias.  A stored [K,M], B [K,N].
// BM=BN=64, BK=16, 256 threads, 4x4 micro-tile per thread.
// ---------------------------------------------------------------------------
__global__ __launch_bounds__(256)
void gemm_tn(const float* __restrict__ A, const float* __restrict__ B,
             const float* __restrict__ bias, float* __restrict__ C,
             int M, int N, int K) {
    constexpr int BM = 64, BN = 64, BK = 16;
    __shared__ float As[BK][BM + 4];
    __shared__ float Bs[BK][BN];
    const int tid = threadIdx.x;
    const int tx = tid & 15;          // 0..15 -> N
    const int ty = tid >> 4;          // 0..15 -> M
    const int m0 = blockIdx.x * BM;
    const int n0 = blockIdx.y * BN;
    float acc[4][4] = {};
    for (int k0 = 0; k0 < K; k0 += BK) {
        {   // load A tile: 16x64 floats, each thread one float4 (row-contig in M)
            int idx = tid * 4;
            int kk = idx >> 6;        // /64
            int mm = idx & 63;
            float4 a4 = *reinterpret_cast<const float4*>(&A[(size_t)(k0 + kk) * M + m0 + mm]);
            *reinterpret_cast<float4*>(&As[kk][mm]) = a4;
        }
        {   // load B tile: 16x64
            int idx = tid * 4;
            int kk = idx >> 6;
            int nn = idx & 63;
            float4 b4 = *reinterpret_cast<const float4*>(&B[(size_t)(k0 + kk) * N + n0 + nn]);
            *reinterpret_cast<float4*>(&Bs[kk][nn]) = b4;
        }
        __syncthreads();
        #pragma unroll
        for (int kk = 0; kk < BK; ++kk) {
            float4 a4 = *reinterpret_cast<const float4*>(&As[kk][ty * 4]);
            float4 b4 = *reinterpret_cast<const float4*>(&Bs[kk][tx * 4]);
            float a[4] = {a4.x, a4.y, a4.z, a4.w};
            float b[4] = {b4.x, b4.y, b4.z, b4.w};
            #pragma unroll
            for (int i = 0; i < 4; ++i)
                #pragma unroll
                for (int j = 0; j < 4; ++j)
                    acc[i][j] += a[i] * b[j];
        }
        __syncthreads();
    }
    #pragma unroll
    for (int i = 0; i < 4; ++i) {
        int m = m0 + ty * 4 + i;
        #pragma unroll
        for (int j = 0; j < 4; ++j) {
            int n = n0 + tx * 4 + j;
            C[(size_t)m * N + n] = acc[i][j] + bias[n];
        }
    }
}

// ---------------------------------------------------------------------------
// Tiled GEMM, NN variant: C[M,N] = A @ B + bias (optional ReLU).
// A stored [M,K], B [K,N].
// ---------------------------------------------------------------------------
template <bool RELU>
__global__ __launch_bounds__(256)
void gemm_nn(const float* __restrict__ A, const float* __restrict__ B,
             const float* __restrict__ bias, float* __restrict__ C,
             int M, int N, int K) {
    constexpr int BM = 64, BN = 64, BK = 16;
    __shared__ float As[BK][BM + 4];   // stored transposed: As[k][m]
    __shared__ float Bs[BK][BN];
    const int tid = threadIdx.x;
    const int tx = tid & 15;
    const int ty = tid >> 4;
    const int m0 = blockIdx.x * BM;
    const int n0 = blockIdx.y * BN;
    float acc[4][4] = {};
    for (int k0 = 0; k0 < K; k0 += BK) {
        {   // load A tile 64x16, thread reads float4 along K, scatters to As[k][m]
            int mm = tid >> 2;            // 0..63
            int kk = (tid & 3) * 4;       // 0,4,8,12
            float4 a4 = *reinterpret_cast<const float4*>(&A[(size_t)(m0 + mm) * K + k0 + kk]);
            As[kk + 0][mm] = a4.x;
            As[kk + 1][mm] = a4.y;
            As[kk + 2][mm] = a4.z;
            As[kk + 3][mm] = a4.w;
        }
        {
            int idx = tid * 4;
            int kk = idx >> 6;
            int nn = idx & 63;
            float4 b4 = *reinterpret_cast<const float4*>(&B[(size_t)(k0 + kk) * N + n0 + nn]);
            *reinterpret_cast<float4*>(&Bs[kk][nn]) = b4;
        }
        __syncthreads();
        #pragma unroll
        for (int kk = 0; kk < BK; ++kk) {
            float4 a4 = *reinterpret_cast<const float4*>(&As[kk][ty * 4]);
            float4 b4 = *reinterpret_cast<const float4*>(&Bs[kk][tx * 4]);
            float a[4] = {a4.x, a4.y, a4.z, a4.w};
            float b[4] = {b4.x, b4.y, b4.z, b4.w};
            #pragma unroll
            for (int i = 0; i < 4; ++i)
                #pragma unroll
                for (int j = 0; j < 4; ++j)
                    acc[i][j] += a[i] * b[j];
        }
        __syncthreads();
    }
    #pragma unroll
    for (int i = 0; i < 4; ++i) {
        int m = m0 + ty * 4 + i;
        #pragma unroll
        for (int j = 0; j < 4; ++j) {
            int n = n0 + tx * 4 + j;
            float r = acc[i][j] + bias[n];
            if (RELU) r = fmaxf(r, 0.0f);
            C[(size_t)m * N + n] = r;
        }
    }
}

// ---------------------------------------------------------------------------
// Flash attention (fp32): one block = (one head, 32 query rows).
// 256 threads: thread t -> (q row r = t>>3, sub-lane j = t&7).
// Loop over 128-key tiles staged in LDS; online softmax.
// ---------------------------------------------------------------------------
__global__ __launch_bounds__(256)
void flash_attn(const float* __restrict__ q, const float* __restrict__ k,
                const float* __restrict__ v, float* __restrict__ o) {
    const int h = blockIdx.y;
    const int q0 = blockIdx.x * 32;
    const int t = threadIdx.x;
    const int r = t >> 3;
    const int j = t & 7;
    __shared__ float Kl[128][33];
    __shared__ float Vl[128][33];
    __shared__ float Pl[32][129];

    float qreg[32];
    {
        const float* qrow = &q[(size_t)(q0 + r) * CCH + h * HD];
        #pragma unroll
        for (int d = 0; d < HD; d += 4) {
            float4 q4 = *reinterpret_cast<const float4*>(&qrow[d]);
            qreg[d] = q4.x; qreg[d + 1] = q4.y; qreg[d + 2] = q4.z; qreg[d + 3] = q4.w;
        }
    }
    float m = -1e30f, l = 0.0f;
    float oacc[4] = {0.f, 0.f, 0.f, 0.f};
    const float scale = 0.17677669529663687f;   // 1/sqrt(32)
    const float LOG2E = 1.4426950408889634f;

    for (int k0 = 0; k0 < SQ; k0 += 128) {
        // stage K and V tiles (128 rows x 32 dims)
        #pragma unroll
        for (int pass = 0; pass < 4; ++pass) {
            int row = pass * 32 + (t >> 3);
            int d = (t & 7) * 4;
            float4 k4 = *reinterpret_cast<const float4*>(&k[(size_t)(k0 + row) * CCH + h * HD + d]);
            Kl[row][d] = k4.x; Kl[row][d + 1] = k4.y; Kl[row][d + 2] = k4.z; Kl[row][d + 3] = k4.w;
            float4 v4 = *reinterpret_cast<const float4*>(&v[(size_t)(k0 + row) * CCH + h * HD + d]);
            Vl[row][d] = v4.x; Vl[row][d + 1] = v4.y; Vl[row][d + 2] = v4.z; Vl[row][d + 3] = v4.w;
        }
        __syncthreads();

        // scores for 16 keys per thread (keys j + 8i)
        float p[16];
        float tmax = -1e30f;
        #pragma unroll
        for (int i = 0; i < 16; ++i) {
            int kk = j + 8 * i;
            float s = 0.f;
            #pragma unroll
            for (int d = 0; d < HD; ++d) s += qreg[d] * Kl[kk][d];
            s *= scale;
            p[i] = s;
            tmax = fmaxf(tmax, s);
        }
        tmax = fmaxf(tmax, __shfl_xor(tmax, 1));
        tmax = fmaxf(tmax, __shfl_xor(tmax, 2));
        tmax = fmaxf(tmax, __shfl_xor(tmax, 4));
        float mnew = fmaxf(m, tmax);
        float alpha = exp2f((m - mnew) * LOG2E);
        float lsum = 0.f;
        #pragma unroll
        for (int i = 0; i < 16; ++i) {
            float pp = exp2f((p[i] - mnew) * LOG2E);
            Pl[r][j + 8 * i] = pp;
            lsum += pp;
        }
        lsum += __shfl_xor(lsum, 1);
        lsum += __shfl_xor(lsum, 2);
        lsum += __shfl_xor(lsum, 4);
        l = l * alpha + lsum;
        m = mnew;
        #pragma unroll
        for (int i = 0; i < 4; ++i) oacc[i] *= alpha;
        __syncthreads();

        // PV: thread accumulates d = j*4 .. j*4+3 for its q row
        const int dbase = j * 4;
        for (int kk = 0; kk < 128; ++kk) {
            float pp = Pl[r][kk];
            #pragma unroll
            for (int i = 0; i < 4; ++i) oacc[i] += pp * Vl[kk][dbase + i];
        }
        __syncthreads();
    }
    float inv = 1.0f / l;
    #pragma unroll
    for (int i = 0; i < 4; ++i)
        o[(size_t)(q0 + r) * CCH + h * HD + j * 4 + i] = oacc[i] * inv;
}

// ---------------------------------------------------------------------------
// Fused residual add + LayerNorm over C=256. One block per row.
// ---------------------------------------------------------------------------
__global__ __launch_bounds__(256)
void add_ln(const float* __restrict__ a, const float* __restrict__ b,
            const float* __restrict__ g, const float* __restrict__ beta,
            float* __restrict__ out) {
    const int s = blockIdx.x;
    const int c = threadIdx.x;
    float val = a[(size_t)s * CCH + c] + b[(size_t)s * CCH + c];
    float sum = val, sq = val * val;
    #pragma unroll
    for (int off = 1; off < 64; off <<= 1) {
        sum += __shfl_xor(sum, off);
        sq  += __shfl_xor(sq, off);
    }
    __shared__ float ssum[4], ssq[4];
    int w = c >> 6;
    if ((c & 63) == 0) { ssum[w] = sum; ssq[w] = sq; }
    __syncthreads();
    sum = ssum[0] + ssum[1] + ssum[2] + ssum[3];
    sq  = ssq[0] + ssq[1] + ssq[2] + ssq[3];
    float mu = sum * (1.0f / CCH);
    float var = sq * (1.0f / CCH) - mu * mu;
    float rs = rsqrtf(var + LN_EPS);
    out[(size_t)s * CCH + c] = (val - mu) * rs * g[c] + beta[c];
}

// ---------------------------------------------------------------------------
// Final transpose: in [S][C] -> out [C][S]  (== [B,C,H,W])
// ---------------------------------------------------------------------------
__global__ __launch_bounds__(256)
void transpose_sc_cs(const float* __restrict__ in, float* __restrict__ out) {
    __shared__ float tile[32][33];
    const int s0 = blockIdx.x * 32;
    const int c0 = blockIdx.y * 32;
    const int tx = threadIdx.x & 31;
    const int ty = threadIdx.x >> 5;   // 0..7
    #pragma unroll
    for (int i = 0; i < 32; i += 8)
        tile[ty + i][tx] = in[(size_t)(s0 + ty + i) * CCH + c0 + tx];
    __syncthreads();
    #pragma unroll
    for (int i = 0; i < 32; i += 8)
        out[(size_t)(c0 + ty + i) * SQ + s0 + tx] = tile[tx][ty + i];
}

// ---------------------------------------------------------------------------
extern "C" void kernel_launch(void* const* d_in, const int* in_sizes, int n_in,
                              void* d_out, int out_size, void* d_ws, size_t ws_size,
                              hipStream_t stream) {
    const float* lidar = (const float*)d_in[0];
    const float* image = (const float*)d_in[1];
    const float* Wq  = (const float*)d_in[2];
    const float* bq  = (const float*)d_in[3];
    const float* Wk  = (const float*)d_in[4];
    const float* bk  = (const float*)d_in[5];
    const float* Wv  = (const float*)d_in[6];
    const float* bv  = (const float*)d_in[7];
    const float* Wo  = (const float*)d_in[8];
    const float* bo  = (const float*)d_in[9];
    const float* g1  = (const float*)d_in[10];
    const float* b1  = (const float*)d_in[11];
    const float* W1  = (const float*)d_in[12];
    const float* bf1 = (const float*)d_in[13];
    const float* W2  = (const float*)d_in[14];
    const float* bf2 = (const float*)d_in[15];
    const float* g2  = (const float*)d_in[16];
    const float* b2  = (const float*)d_in[17];
    float* out = (float*)d_out;

    // workspace layout (aliased; peak 24MB)
    char* ws = (char*)d_ws;
    float* q    = (float*)(ws + (0ull  << 20));  // [S][C] 4MB, live until LN1
    float* k    = (float*)(ws + (4ull  << 20));  // live until attn
    float* v    = (float*)(ws + (8ull  << 20));  // live until attn
    float* attn = (float*)(ws + (12ull << 20));  // live until Wo
    float* o    = (float*)(ws + (16ull << 20));  // live until LN1
    float* ln1  = (float*)(ws + (20ull << 20));  // live until LN2
    float* h1   = (float*)(ws + (0ull  << 20));  // 16MB, reuses q..attn (dead)
    float* h2   = (float*)(ws + (16ull << 20));  // reuses o (dead)
    float* ln2  = (float*)(ws + (0ull  << 20));  // reuses h1 head (dead)

    dim3 blk(256);
    // QKV projections (A^T layout: inputs stored [C][S])
    gemm_tn<<<dim3(64, 4), blk, 0, stream>>>(lidar, Wq, bq, q, SQ, CCH, CCH);
    gemm_tn<<<dim3(64, 4), blk, 0, stream>>>(image, Wk, bk, k, SQ, CCH, CCH);
    gemm_tn<<<dim3(64, 4), blk, 0, stream>>>(image, Wv, bv, v, SQ, CCH, CCH);
    // attention
    flash_attn<<<dim3(SQ / 32, NH), blk, 0, stream>>>(q, k, v, attn);
    // output projection
    gemm_nn<false><<<dim3(64, 4), blk, 0, stream>>>(attn, Wo, bo, o, SQ, CCH, CCH);
    // LN1(q + o)
    add_ln<<<SQ, blk, 0, stream>>>(q, o, g1, b1, ln1);
    // FFN
    gemm_nn<true ><<<dim3(64, 16), blk, 0, stream>>>(ln1, W1, bf1, h1, SQ, 4 * CCH, CCH);
    gemm_nn<false><<<dim3(64, 4),  blk, 0, stream>>>(h1, W2, bf2, h2, SQ, CCH, 4 * CCH);
    // LN2(ln1 + h2)
    add_ln<<<SQ, blk, 0, stream>>>(ln1, h2, g2, b2, ln2);
    // final [S][C] -> [C][S]
    transpose_sc_cs<<<dim3(SQ / 32, CCH / 32), blk, 0, stream>>>(ln2, out);
}

// Round 2
// 298.955 us; speedup vs baseline: 4.2929x; 4.2929x over previous
//
#include <hip/hip_runtime.h>

#define SQ 4096      // sequence length = 64*64
#define CCH 256      // channels
#define NH 8         // heads
#define HD 32        // head dim
#define LN_EPS 1e-5f

typedef __bf16 bf16x8 __attribute__((ext_vector_type(8)));
typedef float f32x4 __attribute__((ext_vector_type(4)));

#if defined(__has_builtin)
#if __has_builtin(__builtin_amdgcn_exp2f)
#define EXP2F(x) __builtin_amdgcn_exp2f(x)
#else
#define EXP2F(x) exp2f(x)
#endif
#else
#define EXP2F(x) exp2f(x)
#endif

// ---------------------------------------------------------------------------
// Tiled GEMM, TN variant: C[M,N] = A^T @ B + bias.  A stored [K,M], B [K,N].
// ---------------------------------------------------------------------------
__global__ __launch_bounds__(256)
void gemm_tn(const float* __restrict__ A, const float* __restrict__ B,
             const float* __restrict__ bias, float* __restrict__ C,
             int M, int N, int K) {
    constexpr int BM = 64, BN = 64, BK = 16;
    __shared__ float As[BK][BM + 4];
    __shared__ float Bs[BK][BN];
    const int tid = threadIdx.x;
    const int tx = tid & 15;          // 0..15 -> N
    const int ty = tid >> 4;          // 0..15 -> M
    const int m0 = blockIdx.x * BM;
    const int n0 = blockIdx.y * BN;
    float acc[4][4] = {};
    for (int k0 = 0; k0 < K; k0 += BK) {
        {
            int idx = tid * 4;
            int kk = idx >> 6;
            int mm = idx & 63;
            float4 a4 = *reinterpret_cast<const float4*>(&A[(size_t)(k0 + kk) * M + m0 + mm]);
            *reinterpret_cast<float4*>(&As[kk][mm]) = a4;
        }
        {
            int idx = tid * 4;
            int kk = idx >> 6;
            int nn = idx & 63;
            float4 b4 = *reinterpret_cast<const float4*>(&B[(size_t)(k0 + kk) * N + n0 + nn]);
            *reinterpret_cast<float4*>(&Bs[kk][nn]) = b4;
        }
        __syncthreads();
        #pragma unroll
        for (int kk = 0; kk < BK; ++kk) {
            float4 a4 = *reinterpret_cast<const float4*>(&As[kk][ty * 4]);
            float4 b4 = *reinterpret_cast<const float4*>(&Bs[kk][tx * 4]);
            float a[4] = {a4.x, a4.y, a4.z, a4.w};
            float b[4] = {b4.x, b4.y, b4.z, b4.w};
            #pragma unroll
            for (int i = 0; i < 4; ++i)
                #pragma unroll
                for (int j = 0; j < 4; ++j)
                    acc[i][j] += a[i] * b[j];
        }
        __syncthreads();
    }
    #pragma unroll
    for (int i = 0; i < 4; ++i) {
        int m = m0 + ty * 4 + i;
        #pragma unroll
        for (int j = 0; j < 4; ++j) {
            int n = n0 + tx * 4 + j;
            C[(size_t)m * N + n] = acc[i][j] + bias[n];
        }
    }
}

// ---------------------------------------------------------------------------
// Tiled GEMM, NN variant: C[M,N] = A @ B + bias (optional ReLU).
// ---------------------------------------------------------------------------
template <bool RELU>
__global__ __launch_bounds__(256)
void gemm_nn(const float* __restrict__ A, const float* __restrict__ B,
             const float* __restrict__ bias, float* __restrict__ C,
             int M, int N, int K) {
    constexpr int BM = 64, BN = 64, BK = 16;
    __shared__ float As[BK][BM + 4];
    __shared__ float Bs[BK][BN];
    const int tid = threadIdx.x;
    const int tx = tid & 15;
    const int ty = tid >> 4;
    const int m0 = blockIdx.x * BM;
    const int n0 = blockIdx.y * BN;
    float acc[4][4] = {};
    for (int k0 = 0; k0 < K; k0 += BK) {
        {
            int mm = tid >> 2;
            int kk = (tid & 3) * 4;
            float4 a4 = *reinterpret_cast<const float4*>(&A[(size_t)(m0 + mm) * K + k0 + kk]);
            As[kk + 0][mm] = a4.x;
            As[kk + 1][mm] = a4.y;
            As[kk + 2][mm] = a4.z;
            As[kk + 3][mm] = a4.w;
        }
        {
            int idx = tid * 4;
            int kk = idx >> 6;
            int nn = idx & 63;
            float4 b4 = *reinterpret_cast<const float4*>(&B[(size_t)(k0 + kk) * N + n0 + nn]);
            *reinterpret_cast<float4*>(&Bs[kk][nn]) = b4;
        }
        __syncthreads();
        #pragma unroll
        for (int kk = 0; kk < BK; ++kk) {
            float4 a4 = *reinterpret_cast<const float4*>(&As[kk][ty * 4]);
            float4 b4 = *reinterpret_cast<const float4*>(&Bs[kk][tx * 4]);
            float a[4] = {a4.x, a4.y, a4.z, a4.w};
            float b[4] = {b4.x, b4.y, b4.z, b4.w};
            #pragma unroll
            for (int i = 0; i < 4; ++i)
                #pragma unroll
                for (int j = 0; j < 4; ++j)
                    acc[i][j] += a[i] * b[j];
        }
        __syncthreads();
    }
    #pragma unroll
    for (int i = 0; i < 4; ++i) {
        int m = m0 + ty * 4 + i;
        #pragma unroll
        for (int j = 0; j < 4; ++j) {
            int n = n0 + tx * 4 + j;
            float r = acc[i][j] + bias[n];
            if (RELU) r = fmaxf(r, 0.0f);
            C[(size_t)m * N + n] = r;
        }
    }
}

// ---------------------------------------------------------------------------
// MFMA flash attention (bf16 inputs, fp32 accumulate).
// Block = (head, 64 q-rows), 4 waves; wave w owns q rows q0+16w..+15.
// KV tile = 64 keys. K/V staged in LDS in MFMA *fragment order* so every
// hot-loop LDS read is a conflict-free consecutive-lane ds_read_b128.
// mfma_f32_16x16x32_bf16: A lane l -> row l&15, k=(l>>4)*8+j;
//                         B lane l -> col l&15, k=(l>>4)*8+j;
//                         D lane l -> col l&15, row=(l>>4)*4+reg.
// ---------------------------------------------------------------------------
__global__ __launch_bounds__(256)
void flash_attn_mfma(const float* __restrict__ q, const float* __restrict__ k,
                     const float* __restrict__ v, float* __restrict__ o) {
    const int h  = blockIdx.y;
    const int q0 = blockIdx.x * 64;
    const int tid = threadIdx.x;
    const int w   = tid >> 6;       // wave id (also staging subtile id)
    const int l   = tid & 63;
    const int l15 = l & 15, lg = l >> 4;

    __shared__ __align__(16) __bf16 Kf[4][64][8];      // QK^T B-frags (4 key subtiles)
    __shared__ __align__(16) __bf16 Vf[2][2][64][8];   // PV B-frags [khalf][dhalf]
    __shared__ __align__(16) __bf16 Pf[4][2][64][8];   // per-wave P A-frags [wave][khalf]

    const float scale = 0.17677669529663687f;   // 1/sqrt(32), folded into Q
    const float LOG2E = 1.4426950408889634f;

    bf16x8 aq;
    {
        const float* qrow = &q[(size_t)(q0 + w * 16 + l15) * CCH + h * HD + lg * 8];
        float4 qa = *reinterpret_cast<const float4*>(qrow);
        float4 qb = *reinterpret_cast<const float4*>(qrow + 4);
        aq[0] = (__bf16)(qa.x * scale); aq[1] = (__bf16)(qa.y * scale);
        aq[2] = (__bf16)(qa.z * scale); aq[3] = (__bf16)(qa.w * scale);
        aq[4] = (__bf16)(qb.x * scale); aq[5] = (__bf16)(qb.y * scale);
        aq[6] = (__bf16)(qb.z * scale); aq[7] = (__bf16)(qb.w * scale);
    }

    float mo[4]  = {-1e30f, -1e30f, -1e30f, -1e30f};
    float lac[4] = {0.f, 0.f, 0.f, 0.f};
    f32x4 oacc[2] = {{0.f, 0.f, 0.f, 0.f}, {0.f, 0.f, 0.f, 0.f}};

    const int kh_s = w >> 1, dh_s = w & 1;   // this wave's V staging piece

    for (int kt = 0; kt < SQ / 64; ++kt) {
        const int kbase = kt * 64;
        __syncthreads();   // prior iteration's Kf/Vf reads complete before restage
        {   // stage K subtile w: lane l -> K[kbase+16w+(l&15)][ (l>>4)*8 .. +7 ]
            const float* krow = &k[(size_t)(kbase + w * 16 + l15) * CCH + h * HD + lg * 8];
            float4 ka = *reinterpret_cast<const float4*>(krow);
            float4 kb = *reinterpret_cast<const float4*>(krow + 4);
            bf16x8 kv8;
            kv8[0] = (__bf16)ka.x; kv8[1] = (__bf16)ka.y;
            kv8[2] = (__bf16)ka.z; kv8[3] = (__bf16)ka.w;
            kv8[4] = (__bf16)kb.x; kv8[5] = (__bf16)kb.y;
            kv8[6] = (__bf16)kb.z; kv8[7] = (__bf16)kb.w;
            *reinterpret_cast<bf16x8*>(&Kf[w][l][0]) = kv8;
        }
        {   // stage V piece (kh_s,dh_s): lane l gathers a V column slice
            const float* vcol = &v[(size_t)(kbase + 32 * kh_s + lg * 8) * CCH + h * HD + dh_s * 16 + l15];
            bf16x8 vv;
            #pragma unroll
            for (int j = 0; j < 8; ++j) vv[j] = (__bf16)vcol[(size_t)j * CCH];
            *reinterpret_cast<bf16x8*>(&Vf[kh_s][dh_s][l][0]) = vv;
        }
        __syncthreads();

        // --- QK^T: S[16q x 64k] for this wave ---
        f32x4 s[4];
        #pragma unroll
        for (int t = 0; t < 4; ++t) {
            bf16x8 kb8 = *reinterpret_cast<const bf16x8*>(&Kf[t][l][0]);
            s[t] = __builtin_amdgcn_mfma_f32_16x16x32_bf16(aq, kb8, (f32x4){0.f, 0.f, 0.f, 0.f}, 0, 0, 0);
        }

        // --- online softmax (rows live across 16-lane groups) ---
        float mn[4], alpha[4];
        #pragma unroll
        for (int r = 0; r < 4; ++r) {
            float rm = fmaxf(fmaxf(s[0][r], s[1][r]), fmaxf(s[2][r], s[3][r]));
            rm = fmaxf(rm, __shfl_xor(rm, 1));
            rm = fmaxf(rm, __shfl_xor(rm, 2));
            rm = fmaxf(rm, __shfl_xor(rm, 4));
            rm = fmaxf(rm, __shfl_xor(rm, 8));
            mn[r] = fmaxf(mo[r], rm);
            alpha[r] = EXP2F((mo[r] - mn[r]) * LOG2E);
        }
        float ps[4] = {0.f, 0.f, 0.f, 0.f};
        #pragma unroll
        for (int t = 0; t < 4; ++t)
            #pragma unroll
            for (int r = 0; r < 4; ++r) {
                float p = EXP2F((s[t][r] - mn[r]) * LOG2E);
                s[t][r] = p;
                ps[r] += p;
            }
        #pragma unroll
        for (int r = 0; r < 4; ++r) {
            float x = ps[r];
            x += __shfl_xor(x, 1); x += __shfl_xor(x, 2);
            x += __shfl_xor(x, 4); x += __shfl_xor(x, 8);
            lac[r] = lac[r] * alpha[r] + x;
            mo[r] = mn[r];
            oacc[0][r] *= alpha[r];
            oacc[1][r] *= alpha[r];
        }

        // --- C/D layout -> A-operand layout via per-wave LDS buffer ---
        #pragma unroll
        for (int t = 0; t < 4; ++t) {
            const int kh = t >> 1;
            const int lp = ((l15 >> 3) | ((t & 1) << 1)) << 4;   // target lane group
            #pragma unroll
            for (int r = 0; r < 4; ++r) {
                const int row = lg * 4 + r;
                Pf[w][kh][lp | row][l & 7] = (__bf16)s[t][r];
            }
        }

        // --- PV: O[16q x 32d] += P @ V ---
        bf16x8 pa0 = *reinterpret_cast<const bf16x8*>(&Pf[w][0][l][0]);
        bf16x8 pa1 = *reinterpret_cast<const bf16x8*>(&Pf[w][1][l][0]);
        #pragma unroll
        for (int dh = 0; dh < 2; ++dh) {
            bf16x8 vb0 = *reinterpret_cast<const bf16x8*>(&Vf[0][dh][l][0]);
            bf16x8 vb1 = *reinterpret_cast<const bf16x8*>(&Vf[1][dh][l][0]);
            oacc[dh] = __builtin_amdgcn_mfma_f32_16x16x32_bf16(pa0, vb0, oacc[dh], 0, 0, 0);
            oacc[dh] = __builtin_amdgcn_mfma_f32_16x16x32_bf16(pa1, vb1, oacc[dh], 0, 0, 0);
        }
    }

    #pragma unroll
    for (int r = 0; r < 4; ++r) {
        const float inv = 1.0f / lac[r];
        const int row = q0 + w * 16 + lg * 4 + r;
        o[(size_t)row * CCH + h * HD + l15]      = oacc[0][r] * inv;
        o[(size_t)row * CCH + h * HD + 16 + l15] = oacc[1][r] * inv;
    }
}

// ---------------------------------------------------------------------------
// Fused residual add + LayerNorm over C=256. One block per row.
// ---------------------------------------------------------------------------
__global__ __launch_bounds__(256)
void add_ln(const float* __restrict__ a, const float* __restrict__ b,
            const float* __restrict__ g, const float* __restrict__ beta,
            float* __restrict__ out) {
    const int s = blockIdx.x;
    const int c = threadIdx.x;
    float val = a[(size_t)s * CCH + c] + b[(size_t)s * CCH + c];
    float sum = val, sq = val * val;
    #pragma unroll
    for (int off = 1; off < 64; off <<= 1) {
        sum += __shfl_xor(sum, off);
        sq  += __shfl_xor(sq, off);
    }
    __shared__ float ssum[4], ssq[4];
    int w = c >> 6;
    if ((c & 63) == 0) { ssum[w] = sum; ssq[w] = sq; }
    __syncthreads();
    sum = ssum[0] + ssum[1] + ssum[2] + ssum[3];
    sq  = ssq[0] + ssq[1] + ssq[2] + ssq[3];
    float mu = sum * (1.0f / CCH);
    float var = sq * (1.0f / CCH) - mu * mu;
    float rs = rsqrtf(var + LN_EPS);
    out[(size_t)s * CCH + c] = (val - mu) * rs * g[c] + beta[c];
}

// ---------------------------------------------------------------------------
// Final transpose: in [S][C] -> out [C][S]
// ---------------------------------------------------------------------------
__global__ __launch_bounds__(256)
void transpose_sc_cs(const float* __restrict__ in, float* __restrict__ out) {
    __shared__ float tile[32][33];
    const int s0 = blockIdx.x * 32;
    const int c0 = blockIdx.y * 32;
    const int tx = threadIdx.x & 31;
    const int ty = threadIdx.x >> 5;
    #pragma unroll
    for (int i = 0; i < 32; i += 8)
        tile[ty + i][tx] = in[(size_t)(s0 + ty + i) * CCH + c0 + tx];
    __syncthreads();
    #pragma unroll
    for (int i = 0; i < 32; i += 8)
        out[(size_t)(c0 + ty + i) * SQ + s0 + tx] = tile[tx][ty + i];
}

// ---------------------------------------------------------------------------
extern "C" void kernel_launch(void* const* d_in, const int* in_sizes, int n_in,
                              void* d_out, int out_size, void* d_ws, size_t ws_size,
                              hipStream_t stream) {
    const float* lidar = (const float*)d_in[0];
    const float* image = (const float*)d_in[1];
    const float* Wq  = (const float*)d_in[2];
    const float* bq  = (const float*)d_in[3];
    const float* Wk  = (const float*)d_in[4];
    const float* bk  = (const float*)d_in[5];
    const float* Wv  = (const float*)d_in[6];
    const float* bv  = (const float*)d_in[7];
    const float* Wo  = (const float*)d_in[8];
    const float* bo  = (const float*)d_in[9];
    const float* g1  = (const float*)d_in[10];
    const float* b1  = (const float*)d_in[11];
    const float* W1  = (const float*)d_in[12];
    const float* bf1 = (const float*)d_in[13];
    const float* W2  = (const float*)d_in[14];
    const float* bf2 = (const float*)d_in[15];
    const float* g2  = (const float*)d_in[16];
    const float* b2  = (const float*)d_in[17];
    float* out = (float*)d_out;

    char* ws = (char*)d_ws;
    float* q    = (float*)(ws + (0ull  << 20));
    float* k    = (float*)(ws + (4ull  << 20));
    float* v    = (float*)(ws + (8ull  << 20));
    float* attn = (float*)(ws + (12ull << 20));
    float* o    = (float*)(ws + (16ull << 20));
    float* ln1  = (float*)(ws + (20ull << 20));
    float* h1   = (float*)(ws + (0ull  << 20));
    float* h2   = (float*)(ws + (16ull << 20));
    float* ln2  = (float*)(ws + (0ull  << 20));

    dim3 blk(256);
    gemm_tn<<<dim3(64, 4), blk, 0, stream>>>(lidar, Wq, bq, q, SQ, CCH, CCH);
    gemm_tn<<<dim3(64, 4), blk, 0, stream>>>(image, Wk, bk, k, SQ, CCH, CCH);
    gemm_tn<<<dim3(64, 4), blk, 0, stream>>>(image, Wv, bv, v, SQ, CCH, CCH);
    flash_attn_mfma<<<dim3(SQ / 64, NH), blk, 0, stream>>>(q, k, v, attn);
    gemm_nn<false><<<dim3(64, 4), blk, 0, stream>>>(attn, Wo, bo, o, SQ, CCH, CCH);
    add_ln<<<SQ, blk, 0, stream>>>(q, o, g1, b1, ln1);
    gemm_nn<true ><<<dim3(64, 16), blk, 0, stream>>>(ln1, W1, bf1, h1, SQ, 4 * CCH, CCH);
    gemm_nn<false><<<dim3(64, 4),  blk, 0, stream>>>(h1, W2, bf2, h2, SQ, CCH, 4 * CCH);
    add_ln<<<SQ, blk, 0, stream>>>(ln1, h2, g2, b2, ln2);
    transpose_sc_cs<<<dim3(SQ / 32, CCH / 32), blk, 0, stream>>>(ln2, out);
}

// Round 3
// 208.803 us; speedup vs baseline: 6.1464x; 1.4318x over previous
//
#include <hip/hip_runtime.h>

#define SQ 4096      // sequence length = 64*64
#define CCH 256      // channels
#define NH 8         // heads
#define HD 32        // head dim
#define LN_EPS 1e-5f

typedef __bf16 bf16x8 __attribute__((ext_vector_type(8)));
typedef float f32x4 __attribute__((ext_vector_type(4)));
using bf16 = __bf16;

#if defined(__has_builtin)
#if __has_builtin(__builtin_amdgcn_exp2f)
#define EXP2F(x) __builtin_amdgcn_exp2f(x)
#else
#define EXP2F(x) exp2f(x)
#endif
#else
#define EXP2F(x) exp2f(x)
#endif

// ---------------------------------------------------------------------------
// Tile transpose + fp32->bf16 convert: src [R][Ccol] f32 -> dst [Ccol][R] bf16
// One 32x32 tile per call. 256 threads.
// ---------------------------------------------------------------------------
__device__ __forceinline__ void tile_tc(const float* __restrict__ src, bf16* __restrict__ dst,
                                        int R, int Ccol, int ti, int tj) {
    __shared__ float t[32][33];
    const int tx = threadIdx.x & 31;
    const int ty = threadIdx.x >> 5;   // 0..7
    const int i0 = ti * 32, j0 = tj * 32;
    #pragma unroll
    for (int i = 0; i < 32; i += 8)
        t[ty + i][tx] = src[(size_t)(i0 + ty + i) * Ccol + j0 + tx];
    __syncthreads();
    #pragma unroll
    for (int i = 0; i < 32; i += 8)
        dst[(size_t)(j0 + ty + i) * R + i0 + tx] = (bf16)t[tx][ty + i];
}

// inputs: x,y [C][S] f32 -> xT,yT [S][C] bf16
__global__ __launch_bounds__(256)
void cvt_inputs(const float* __restrict__ x, const float* __restrict__ y,
                bf16* __restrict__ xT, bf16* __restrict__ yT) {
    const float* s = blockIdx.z ? y : x;
    bf16* d = blockIdx.z ? yT : xT;
    tile_tc(s, d, CCH, SQ, blockIdx.y, blockIdx.x);
}

// weights: W [K][N] f32 -> WT [N][K] bf16, all six in one launch (768 tiles)
__global__ __launch_bounds__(256)
void cvt_weights(const float* Wq, const float* Wk, const float* Wv, const float* Wo,
                 const float* W1, const float* W2,
                 bf16* WqT, bf16* WkT, bf16* WvT, bf16* WoT, bf16* W1T, bf16* W2T) {
    const int id = blockIdx.x;
    if (id < 256) {                       // four 256x256 weights, 64 tiles each
        const int w = id >> 6, local = id & 63;
        const float* s = (w == 0) ? Wq : (w == 1) ? Wk : (w == 2) ? Wv : Wo;
        bf16* d = (w == 0) ? WqT : (w == 1) ? WkT : (w == 2) ? WvT : WoT;
        tile_tc(s, d, 256, 256, local >> 3, local & 7);
    } else if (id < 512) {                // W1: 256x1024, 8x32 tiles
        const int local = id - 256;
        tile_tc(W1, W1T, 256, 1024, local >> 5, local & 31);
    } else {                              // W2: 1024x256, 32x8 tiles
        const int local = id - 512;
        tile_tc(W2, W2T, 1024, 256, local >> 3, local & 7);
    }
}

// ---------------------------------------------------------------------------
// MFMA GEMM: C[M,N] = A @ B + bias, A [M][K] bf16 row-major, BT [N][K] bf16
// (i.e. B pre-transposed).  64x64 tile, 4 waves (2x2), register-direct
// fragments (no LDS).  fp32 accumulate.
// OUT_MODE: 0 = f32 out; 1 = f32 out + bf16 out (bf16 scaled by bscale);
//           2 = bf16 out; 3 = bf16 out transposed ([N][SQ]).
// ---------------------------------------------------------------------------
template <int K, int OUT_MODE, bool RELU>
__global__ __launch_bounds__(256)
void gemm_mfma(const bf16* __restrict__ A, const bf16* __restrict__ BT,
               const float* __restrict__ bias, float* __restrict__ Cf,
               bf16* __restrict__ Cb, int N, float bscale) {
    const int tid = threadIdx.x;
    const int w = tid >> 6, l = tid & 63;
    const int l15 = l & 15, lg = l >> 4;
    const int m0 = blockIdx.x * 64 + (w >> 1) * 32;
    const int n0 = blockIdx.y * 64 + (w & 1) * 32;

    f32x4 acc[2][2] = {};
    const bf16* a0 = &A[(size_t)(m0 + l15) * K + lg * 8];
    const bf16* b0 = &BT[(size_t)(n0 + l15) * K + lg * 8];

    for (int k0 = 0; k0 < K; k0 += 32) {
        bf16x8 a[2], b[2];
        a[0] = *reinterpret_cast<const bf16x8*>(a0 + k0);
        a[1] = *reinterpret_cast<const bf16x8*>(a0 + (size_t)16 * K + k0);
        b[0] = *reinterpret_cast<const bf16x8*>(b0 + k0);
        b[1] = *reinterpret_cast<const bf16x8*>(b0 + (size_t)16 * K + k0);
        #pragma unroll
        for (int i = 0; i < 2; ++i)
            #pragma unroll
            for (int j = 0; j < 2; ++j)
                acc[i][j] = __builtin_amdgcn_mfma_f32_16x16x32_bf16(a[i], b[j], acc[i][j], 0, 0, 0);
    }

    #pragma unroll
    for (int i = 0; i < 2; ++i) {
        #pragma unroll
        for (int j = 0; j < 2; ++j) {
            const int col = n0 + j * 16 + l15;
            const float bs = bias[col];
            #pragma unroll
            for (int r = 0; r < 4; ++r) {
                const int row = m0 + i * 16 + lg * 4 + r;
                float val = acc[i][j][r] + bs;
                if (RELU) val = fmaxf(val, 0.f);
                if constexpr (OUT_MODE == 0 || OUT_MODE == 1)
                    Cf[(size_t)row * N + col] = val;
                if constexpr (OUT_MODE == 1)
                    Cb[(size_t)row * N + col] = (bf16)(val * bscale);
                if constexpr (OUT_MODE == 2)
                    Cb[(size_t)row * N + col] = (bf16)val;
                if constexpr (OUT_MODE == 3)
                    Cb[(size_t)col * SQ + row] = (bf16)val;
            }
        }
    }
}

// ---------------------------------------------------------------------------
// MFMA flash attention, v2: all operands bf16 in fragment-friendly layouts.
// qb [S][C] bf16 (pre-scaled by 1/sqrt(32)), kb [S][C] bf16, vT [C][S] bf16.
// Direct global fragment loads (K/V are L2-resident; no LDS staging).
// Only LDS: per-wave P relayout buffer (8KB) -> zero barriers.
// Block = (64 q-rows, head); wave w owns rows q0+16w..+15.
// ---------------------------------------------------------------------------
__global__ __launch_bounds__(256)
void flash_attn2(const bf16* __restrict__ qb, const bf16* __restrict__ kb,
                 const bf16* __restrict__ vT, bf16* __restrict__ ob) {
    const int h  = blockIdx.y;
    const int q0 = blockIdx.x * 64;
    const int tid = threadIdx.x;
    const int w = tid >> 6, l = tid & 63;
    const int l15 = l & 15, lg = l >> 4;

    __shared__ __align__(16) bf16 Pf[4][2][64][8];

    const float LOG2E = 1.4426950408889634f;

    bf16x8 aq = *reinterpret_cast<const bf16x8*>(
        &qb[(size_t)(q0 + w * 16 + l15) * CCH + h * HD + lg * 8]);

    float mo[4]  = {-1e30f, -1e30f, -1e30f, -1e30f};
    float lac[4] = {0.f, 0.f, 0.f, 0.f};
    f32x4 oacc[2] = {{0.f, 0.f, 0.f, 0.f}, {0.f, 0.f, 0.f, 0.f}};

    const bf16* kfrag_base = &kb[(size_t)l15 * CCH + h * HD + lg * 8];
    const bf16* vfrag_base = &vT[(size_t)(h * HD + l15) * SQ + lg * 8];

    for (int kt = 0; kt < SQ / 64; ++kt) {
        const int kb0 = kt * 64;

        // --- QK^T: S[16q x 64k] ---
        f32x4 s[4];
        #pragma unroll
        for (int t = 0; t < 4; ++t) {
            bf16x8 kf = *reinterpret_cast<const bf16x8*>(
                kfrag_base + (size_t)(kb0 + t * 16) * CCH);
            s[t] = __builtin_amdgcn_mfma_f32_16x16x32_bf16(aq, kf, (f32x4){0.f, 0.f, 0.f, 0.f}, 0, 0, 0);
        }

        // --- online softmax (rows live across 16-lane groups) ---
        float mn[4], alpha[4];
        #pragma unroll
        for (int r = 0; r < 4; ++r) {
            float rm = fmaxf(fmaxf(s[0][r], s[1][r]), fmaxf(s[2][r], s[3][r]));
            rm = fmaxf(rm, __shfl_xor(rm, 1));
            rm = fmaxf(rm, __shfl_xor(rm, 2));
            rm = fmaxf(rm, __shfl_xor(rm, 4));
            rm = fmaxf(rm, __shfl_xor(rm, 8));
            mn[r] = fmaxf(mo[r], rm);
            alpha[r] = EXP2F((mo[r] - mn[r]) * LOG2E);
        }
        float ps[4] = {0.f, 0.f, 0.f, 0.f};
        #pragma unroll
        for (int t = 0; t < 4; ++t)
            #pragma unroll
            for (int r = 0; r < 4; ++r) {
                float p = EXP2F((s[t][r] - mn[r]) * LOG2E);
                s[t][r] = p;
                ps[r] += p;
            }
        #pragma unroll
        for (int r = 0; r < 4; ++r) {
            float x = ps[r];
            x += __shfl_xor(x, 1); x += __shfl_xor(x, 2);
            x += __shfl_xor(x, 4); x += __shfl_xor(x, 8);
            lac[r] = lac[r] * alpha[r] + x;
            mo[r] = mn[r];
            oacc[0][r] *= alpha[r];
            oacc[1][r] *= alpha[r];
        }

        // --- C/D layout -> A-operand layout via per-wave LDS (no barrier) ---
        #pragma unroll
        for (int t = 0; t < 4; ++t) {
            const int kh = t >> 1;
            const int lp = ((l15 >> 3) | ((t & 1) << 1)) << 4;
            #pragma unroll
            for (int r = 0; r < 4; ++r) {
                const int row = lg * 4 + r;
                Pf[w][kh][lp | row][l & 7] = (bf16)s[t][r];
            }
        }

        // --- PV: O[16q x 32d] += P @ V ---
        bf16x8 pa0 = *reinterpret_cast<const bf16x8*>(&Pf[w][0][l][0]);
        bf16x8 pa1 = *reinterpret_cast<const bf16x8*>(&Pf[w][1][l][0]);
        #pragma unroll
        for (int dh = 0; dh < 2; ++dh) {
            bf16x8 vb0 = *reinterpret_cast<const bf16x8*>(
                vfrag_base + (size_t)dh * 16 * SQ + kb0);
            bf16x8 vb1 = *reinterpret_cast<const bf16x8*>(
                vfrag_base + (size_t)dh * 16 * SQ + kb0 + 32);
            oacc[dh] = __builtin_amdgcn_mfma_f32_16x16x32_bf16(pa0, vb0, oacc[dh], 0, 0, 0);
            oacc[dh] = __builtin_amdgcn_mfma_f32_16x16x32_bf16(pa1, vb1, oacc[dh], 0, 0, 0);
        }
    }

    #pragma unroll
    for (int r = 0; r < 4; ++r) {
        const float inv = 1.0f / lac[r];
        const int row = q0 + w * 16 + lg * 4 + r;
        ob[(size_t)row * CCH + h * HD + l15]      = (bf16)(oacc[0][r] * inv);
        ob[(size_t)row * CCH + h * HD + 16 + l15] = (bf16)(oacc[1][r] * inv);
    }
}

// ---------------------------------------------------------------------------
// Fused residual add + LayerNorm over C=256; optional bf16 secondary output.
// ---------------------------------------------------------------------------
template <bool DUAL>
__global__ __launch_bounds__(256)
void add_ln(const float* __restrict__ a, const float* __restrict__ b,
            const float* __restrict__ g, const float* __restrict__ beta,
            float* __restrict__ out, bf16* __restrict__ outb) {
    const int s = blockIdx.x;
    const int c = threadIdx.x;
    float val = a[(size_t)s * CCH + c] + b[(size_t)s * CCH + c];
    float sum = val, sq = val * val;
    #pragma unroll
    for (int off = 1; off < 64; off <<= 1) {
        sum += __shfl_xor(sum, off);
        sq  += __shfl_xor(sq, off);
    }
    __shared__ float ssum[4], ssq[4];
    int w = c >> 6;
    if ((c & 63) == 0) { ssum[w] = sum; ssq[w] = sq; }
    __syncthreads();
    sum = ssum[0] + ssum[1] + ssum[2] + ssum[3];
    sq  = ssq[0] + ssq[1] + ssq[2] + ssq[3];
    float mu = sum * (1.0f / CCH);
    float var = sq * (1.0f / CCH) - mu * mu;
    float rs = rsqrtf(var + LN_EPS);
    float res = (val - mu) * rs * g[c] + beta[c];
    out[(size_t)s * CCH + c] = res;
    if constexpr (DUAL) outb[(size_t)s * CCH + c] = (bf16)res;
}

// ---------------------------------------------------------------------------
// Final transpose: in [S][C] f32 -> out [C][S] f32
// ---------------------------------------------------------------------------
__global__ __launch_bounds__(256)
void transpose_sc_cs(const float* __restrict__ in, float* __restrict__ out) {
    __shared__ float tile[32][33];
    const int s0 = blockIdx.x * 32;
    const int c0 = blockIdx.y * 32;
    const int tx = threadIdx.x & 31;
    const int ty = threadIdx.x >> 5;
    #pragma unroll
    for (int i = 0; i < 32; i += 8)
        tile[ty + i][tx] = in[(size_t)(s0 + ty + i) * CCH + c0 + tx];
    __syncthreads();
    #pragma unroll
    for (int i = 0; i < 32; i += 8)
        out[(size_t)(c0 + ty + i) * SQ + s0 + tx] = tile[tx][ty + i];
}

// ---------------------------------------------------------------------------
extern "C" void kernel_launch(void* const* d_in, const int* in_sizes, int n_in,
                              void* d_out, int out_size, void* d_ws, size_t ws_size,
                              hipStream_t stream) {
    const float* lidar = (const float*)d_in[0];
    const float* image = (const float*)d_in[1];
    const float* Wq  = (const float*)d_in[2];
    const float* bq  = (const float*)d_in[3];
    const float* Wk  = (const float*)d_in[4];
    const float* bk  = (const float*)d_in[5];
    const float* Wv  = (const float*)d_in[6];
    const float* bv  = (const float*)d_in[7];
    const float* Wo  = (const float*)d_in[8];
    const float* bo  = (const float*)d_in[9];
    const float* g1  = (const float*)d_in[10];
    const float* b1  = (const float*)d_in[11];
    const float* W1  = (const float*)d_in[12];
    const float* bf1 = (const float*)d_in[13];
    const float* W2  = (const float*)d_in[14];
    const float* bf2 = (const float*)d_in[15];
    const float* g2  = (const float*)d_in[16];
    const float* b2  = (const float*)d_in[17];
    float* out = (float*)d_out;

    // workspace layout (aliased; peak 17.5 MB)
    char* ws = (char*)d_ws;
    const size_t KB = 1024, MBy = 1024 * 1024;
    bf16* xT   = (bf16*)(ws + 0);                    // [0,2M)   dead after q-gemm
    bf16* yT   = (bf16*)(ws + 2 * MBy);              // [2,4M)   dead after v-gemm
    bf16* WqT  = (bf16*)(ws + 4 * MBy);
    bf16* WkT  = (bf16*)(ws + 4 * MBy + 128 * KB);
    bf16* WvT  = (bf16*)(ws + 4 * MBy + 256 * KB);
    bf16* WoT  = (bf16*)(ws + 4 * MBy + 384 * KB);
    bf16* W1T  = (bf16*)(ws + 4 * MBy + 512 * KB);   // 512KB
    bf16* W2T  = (bf16*)(ws + 5 * MBy);              // 512KB -> weights end 5.5M
    float* qf  = (float*)(ws + 5 * MBy + 512 * KB);  // [5.5,9.5M)  dead after ln1
    bf16* qb   = (bf16*)(ws + 9 * MBy + 512 * KB);   // [9.5,11.5M) dead after flash
    bf16* kbb  = (bf16*)(ws + 11 * MBy + 512 * KB);  // [11.5,13.5M) dead after flash
    bf16* vTb  = (bf16*)(ws + 13 * MBy + 512 * KB);  // [13.5,15.5M) dead after flash
    bf16* atb  = (bf16*)(ws + 0);                    // [0,2M)   reuses xT; dead after Wo
    float* o   = (float*)(ws + 9 * MBy + 512 * KB);  // [9.5,13.5M) reuses qb/kbb; dead after ln1
    float* ln1 = (float*)(ws + 13 * MBy + 512 * KB); // [13.5,17.5M) reuses vTb; live till ln2
    bf16* ln1b = (bf16*)(ws + 0);                    // [0,2M)   reuses atb; dead after ffn1
    bf16* h1   = (bf16*)(ws + 5 * MBy + 512 * KB);   // [5.5,13.5M) reuses qf+o; dead after ffn2
    float* h2  = (float*)(ws + 0);                   // [0,4M)   reuses ln1b+yT; dead after ln2
    float* ln2 = (float*)(ws + 5 * MBy + 512 * KB);  // [5.5,9.5M) reuses h1 head

    const float qscale = 0.17677669529663687f;   // 1/sqrt(32)
    dim3 blk(256);

    cvt_inputs<<<dim3(SQ / 32, CCH / 32, 2), blk, 0, stream>>>(lidar, image, xT, yT);
    cvt_weights<<<dim3(768), blk, 0, stream>>>(Wq, Wk, Wv, Wo, W1, W2,
                                               WqT, WkT, WvT, WoT, W1T, W2T);
    // projections
    gemm_mfma<256, 1, false><<<dim3(64, 4), blk, 0, stream>>>(xT, WqT, bq, qf, qb, 256, qscale);
    gemm_mfma<256, 2, false><<<dim3(64, 4), blk, 0, stream>>>(yT, WkT, bk, nullptr, kbb, 256, 1.f);
    gemm_mfma<256, 3, false><<<dim3(64, 4), blk, 0, stream>>>(yT, WvT, bv, nullptr, vTb, 256, 1.f);
    // attention
    flash_attn2<<<dim3(SQ / 64, NH), blk, 0, stream>>>(qb, kbb, vTb, atb);
    // output projection
    gemm_mfma<256, 0, false><<<dim3(64, 4), blk, 0, stream>>>(atb, WoT, bo, o, nullptr, 256, 1.f);
    // LN1(q + o) -> f32 + bf16
    add_ln<true><<<SQ, blk, 0, stream>>>(qf, o, g1, b1, ln1, ln1b);
    // FFN
    gemm_mfma<256, 2, true ><<<dim3(64, 16), blk, 0, stream>>>(ln1b, W1T, bf1, nullptr, h1, 1024, 1.f);
    gemm_mfma<1024, 0, false><<<dim3(64, 4), blk, 0, stream>>>(h1, W2T, bf2, h2, nullptr, 256, 1.f);
    // LN2(ln1 + h2)
    add_ln<false><<<SQ, blk, 0, stream>>>(ln1, h2, g2, b2, ln2, nullptr);
    // final [S][C] -> [C][S]
    transpose_sc_cs<<<dim3(SQ / 32, CCH / 32), blk, 0, stream>>>(ln2, out);
}